// Round 1
// baseline (43.885 us; speedup 1.0000x reference)
//
#include <hip/hip_runtime.h>
#include <hip/hip_bf16.h>
#include <math.h>

#define NTOK   1024
#define DMODEL 256
#define NFREQ  128
#define FOUR_PI_F 12.566370614359172f
#define INV_2PI_F 0.15915494309189535f
#define EPS_F  1e-6f
#define LN_EPS_F 1e-5f

// One block per target residue i. 256 threads: tid<128 accumulate real (cos),
// tid>=128 accumulate imag (sin), each thread owns exactly one output feature.
// Stage (r/2pi, w) for all 1024 sources in LDS once, then 1024-iter trig loop.
// Fused LayerNorm via block reduction at the end.
__global__ __launch_bounds__(256) void wf_ln_kernel(
    const float* __restrict__ coords,       // [N,3]
    const float* __restrict__ wavenumbers,  // [NFREQ]
    const float* __restrict__ gamma,        // [DMODEL]
    const float* __restrict__ beta,         // [DMODEL]
    const unsigned char* __restrict__ mask, // [N], nonzero = padded
    float* __restrict__ out)                // [N, DMODEL]
{
    const int i   = blockIdx.x;
    const int tid = threadIdx.x;
    const int f   = tid & (NFREQ - 1);

    __shared__ float2 sh_rw[NTOK];   // (r * 1/2pi, w)
    __shared__ float  red[4];

    const float tx = coords[i*3+0];
    const float ty = coords[i*3+1];
    const float tz = coords[i*3+2];

    // Cooperative precompute of per-source distance + Green's-function weight.
    for (int j = tid; j < NTOK; j += 256) {
        float dx = coords[j*3+0] - tx;
        float dy = coords[j*3+1] - ty;
        float dz = coords[j*3+2] - tz;
        float r  = sqrtf(dx*dx + dy*dy + dz*dz);
        bool valid = (mask[j] == 0) && (r > EPS_F);
        float w  = valid ? (1.0f / (FOUR_PI_F * r)) : 0.0f;
        sh_rw[j] = make_float2(r * INV_2PI_F, w);
    }
    __syncthreads();

    const float kf = wavenumbers[f];   // phase (revolutions) = (r/2pi) * kf
    float acc = 0.0f;

    if (tid < NFREQ) {
        #pragma unroll 8
        for (int j = 0; j < NTOK; ++j) {
            float2 rw = sh_rw[j];                       // LDS broadcast
            float t = __builtin_amdgcn_fractf(rw.x * kf);
            acc = fmaf(__builtin_amdgcn_cosf(t), rw.y, acc);
        }
    } else {
        #pragma unroll 8
        for (int j = 0; j < NTOK; ++j) {
            float2 rw = sh_rw[j];
            float t = __builtin_amdgcn_fractf(rw.x * kf);
            acc = fmaf(__builtin_amdgcn_sinf(t), rw.y, acc);
        }
    }

    // Target padded -> wf row is zeroed before LN (LN then yields beta).
    if (mask[i] != 0) acc = 0.0f;

    // ---- fused LayerNorm over the 256 per-thread values (two-pass) ----
    const int lane = tid & 63;
    const int wave = tid >> 6;

    float s = acc;
    #pragma unroll
    for (int off = 32; off > 0; off >>= 1) s += __shfl_down(s, off);
    if (lane == 0) red[wave] = s;
    __syncthreads();
    const float mu = (red[0] + red[1] + red[2] + red[3]) * (1.0f / DMODEL);
    __syncthreads();

    const float d = acc - mu;
    float s2 = d * d;
    #pragma unroll
    for (int off = 32; off > 0; off >>= 1) s2 += __shfl_down(s2, off);
    if (lane == 0) red[wave] = s2;
    __syncthreads();
    const float var  = (red[0] + red[1] + red[2] + red[3]) * (1.0f / DMODEL);
    const float rstd = rsqrtf(var + LN_EPS_F);

    out[i*DMODEL + tid] = d * rstd * gamma[tid] + beta[tid];
}

extern "C" void kernel_launch(void* const* d_in, const int* in_sizes, int n_in,
                              void* d_out, int out_size, void* d_ws, size_t ws_size,
                              hipStream_t stream) {
    const float* coords      = (const float*)d_in[0];
    const float* wavenumbers = (const float*)d_in[1];
    const float* gamma1      = (const float*)d_in[2];
    const float* beta1       = (const float*)d_in[3];
    const unsigned char* kpm = (const unsigned char*)d_in[4];
    float* out = (float*)d_out;

    wf_ln_kernel<<<NTOK, 256, 0, stream>>>(coords, wavenumbers, gamma1, beta1, kpm, out);
}